// Round 2
// baseline (1063.192 us; speedup 1.0000x reference)
//
#include <hip/hip_runtime.h>
#include <hip/hip_bf16.h>

// out[b,i,j,d] = U'[seq[b,i]][d] + V[seq[b,j]][d] + w128[d]*log(|idx_i-idx_j|+1)
//   U'[t][d] = b[d] + sum_{c<64} W[d][c]  *emb[t][c]
//   V [t][d] =        sum_{c<64} W[d][64+c]*emb[t][c]
//   w128[d]  = W[d][128]
// B=2, L=1024, D_SEQ=21, D_EMB=64, D_MODEL=128.
// R1 post-mortem: NaN output => float inputs are genuine fp32 (bf16-misread of fp32
// mantissa bits => inf/NaN). This version PROBES the dtype on-device (count of
// huge-magnitude bf16 interpretations of emb_table) and supports both modes.
// fp32 mode: 1 GiB output, write-bound floor ~163 us.

#define BDIM 256
#define LROW 1024
#define NROWS 2048          // B*L
#define DSEQ 21
#define DMOD 128
#define WCOLS 129
#define NTAB (DSEQ * DMOD)  // 2688 floats per table
#define EMB_ELEMS (DSEQ * 64)  // 1344
#define FLAG_SLOT (2 * NTAB + DMOD)  // ws float index holding mode flag

typedef __attribute__((ext_vector_type(4))) float float4v;
typedef __attribute__((ext_vector_type(8))) unsigned short ushort8v;

__device__ __forceinline__ float bf2f(unsigned short u) {
    union { unsigned int i; float f; } x;
    x.i = ((unsigned int)u) << 16;
    return x.f;
}

// ---------------- Kernel 1: dtype probe + tiny table precompute ----------------
// tabs (floats in d_ws): [0,NTAB)=U' (bias folded), [NTAB,2NTAB)=V,
//                        [2NTAB,2NTAB+128)=w128, [FLAG_SLOT]=is_fp32 flag
__global__ __launch_bounds__(BDIM) void precompute_tables(
    const void* __restrict__ emb_v,
    const void* __restrict__ W_v,
    const void* __restrict__ b_v,
    float* __restrict__ tabs)
{
    // --- dtype probe (redundant per block; trivial cost) ---
    // Reading EMB_ELEMS ushorts = 2688 B, safe under both dtypes
    // (bf16 buffer = 2688 B, fp32 buffer = 5376 B).
    __shared__ int s_cnt;
    if (threadIdx.x == 0) s_cnt = 0;
    __syncthreads();
    {
        const unsigned short* eu = (const unsigned short*)emb_v;
        int local = 0;
        for (int p = threadIdx.x; p < EMB_ELEMS; p += BDIM) {
            float x = bf2f(eu[p]);
            if (!(fabsf(x) < 1e4f)) local++;  // catches NaN/inf too
        }
        if (local) atomicAdd(&s_cnt, local);
    }
    __syncthreads();
    const bool is_fp32 = (s_cnt >= 8);  // bf16 normals: 0; fp32 bits: ~295

    int p = blockIdx.x * BDIM + threadIdx.x;
    if (p == 0) tabs[FLAG_SLOT] = is_fp32 ? 1.0f : 0.0f;
    if (p < DMOD) {
        tabs[2 * NTAB + p] = is_fp32 ? ((const float*)W_v)[p * WCOLS + 128]
                                     : bf2f(((const unsigned short*)W_v)[p * WCOLS + 128]);
    }
    if (p >= NTAB) return;
    int t = p >> 7;        // p / 128
    int d = p & 127;
    float su = 0.f, sv = 0.f, bd;
    if (is_fp32) {
        const float* wrow = (const float*)W_v + d * WCOLS;
        const float* erow = (const float*)emb_v + t * 64;
        #pragma unroll 8
        for (int c = 0; c < 64; ++c) {
            float e = erow[c];
            su = fmaf(wrow[c], e, su);
            sv = fmaf(wrow[64 + c], e, sv);
        }
        bd = ((const float*)b_v)[d];
    } else {
        const unsigned short* wrow = (const unsigned short*)W_v + d * WCOLS;
        const unsigned short* erow = (const unsigned short*)emb_v + t * 64;
        #pragma unroll 8
        for (int c = 0; c < 64; ++c) {
            float e = bf2f(erow[c]);
            su = fmaf(bf2f(wrow[c]), e, su);
            sv = fmaf(bf2f(wrow[64 + c]), e, sv);
        }
        bd = bf2f(((const unsigned short*)b_v)[d]);
    }
    tabs[p]        = su + bd;
    tabs[NTAB + p] = sv;
}

// ---------------- Kernel 2: streaming output writer ----------------
// One block per output row (b,i). lane = (jl = tid>>4, d8 = tid&15).
// fp32 mode: each thread writes 8 contiguous floats (2x dwordx4) per iter.
// bf16 mode: each thread writes 8 contiguous bf16 (1x dwordx4) per iter.
__global__ __launch_bounds__(BDIM) void pair_main(
    const int* __restrict__ seq,
    const int* __restrict__ idx,
    const float* __restrict__ tabs,
    void* __restrict__ out_v)
{
    __shared__ float Ush[NTAB];
    __shared__ float Vsh[NTAB];
    const int tid = threadIdx.x;
    for (int p = tid; p < NTAB; p += BDIM) {
        Ush[p] = tabs[p];
        Vsh[p] = tabs[NTAB + p];
    }
    const int d8 = tid & 15;
    const int jl = tid >> 4;
    const float4v w0 = *(const float4v*)(tabs + 2 * NTAB + d8 * 8);
    const float4v w1 = *(const float4v*)(tabs + 2 * NTAB + d8 * 8 + 4);
    const bool is_fp32 = tabs[FLAG_SLOT] != 0.0f;  // grid-uniform
    __syncthreads();

    const int r     = blockIdx.x;   // row in [0, 2048)
    const int bb    = r >> 10;      // batch
    const int seq_i = seq[r];
    const int idx_i = idx[r];
    const float4v u0 = *(const float4v*)(Ush + seq_i * DMOD + d8 * 8);
    const float4v u1 = *(const float4v*)(Ush + seq_i * DMOD + d8 * 8 + 4);

    const int* __restrict__ seq_row = seq + bb * LROW;
    const int* __restrict__ idx_row = idx + bb * LROW;

    if (is_fp32) {
        float* __restrict__ outrow = (float*)out_v + (size_t)r * (LROW * DMOD) + d8 * 8;
        #pragma unroll 2
        for (int jb = 0; jb < LROW; jb += 16) {
            const int jj = jb + jl;
            const int sj = seq_row[jj];
            const int ij = idx_row[jj];
            const float s = __logf(fabsf((float)(idx_i - ij)) + 1.0f);
            const float* vp = Vsh + sj * DMOD + d8 * 8;
            const float4v v0 = *(const float4v*)vp;
            const float4v v1 = *(const float4v*)(vp + 4);
            float4v o0, o1;
            o0[0] = u0[0] + fmaf(w0[0], s, v0[0]);
            o0[1] = u0[1] + fmaf(w0[1], s, v0[1]);
            o0[2] = u0[2] + fmaf(w0[2], s, v0[2]);
            o0[3] = u0[3] + fmaf(w0[3], s, v0[3]);
            o1[0] = u1[0] + fmaf(w1[0], s, v1[0]);
            o1[1] = u1[1] + fmaf(w1[1], s, v1[1]);
            o1[2] = u1[2] + fmaf(w1[2], s, v1[2]);
            o1[3] = u1[3] + fmaf(w1[3], s, v1[3]);
            float* op = outrow + (size_t)jj * DMOD;
            *(float4v*)op       = o0;
            *(float4v*)(op + 4) = o1;
        }
    } else {
        unsigned short* __restrict__ outrow =
            (unsigned short*)out_v + (size_t)r * (LROW * DMOD) + d8 * 8;
        #pragma unroll 2
        for (int jb = 0; jb < LROW; jb += 16) {
            const int jj = jb + jl;
            const int sj = seq_row[jj];
            const int ij = idx_row[jj];
            const float s = __logf(fabsf((float)(idx_i - ij)) + 1.0f);
            const float* vp = Vsh + sj * DMOD + d8 * 8;
            const float4v v0 = *(const float4v*)vp;
            const float4v v1 = *(const float4v*)(vp + 4);
            float o0 = u0[0] + fmaf(w0[0], s, v0[0]);
            float o1 = u0[1] + fmaf(w0[1], s, v0[1]);
            float o2 = u0[2] + fmaf(w0[2], s, v0[2]);
            float o3 = u0[3] + fmaf(w0[3], s, v0[3]);
            float o4 = u1[0] + fmaf(w1[0], s, v1[0]);
            float o5 = u1[1] + fmaf(w1[1], s, v1[1]);
            float o6 = u1[2] + fmaf(w1[2], s, v1[2]);
            float o7 = u1[3] + fmaf(w1[3], s, v1[3]);
            union { __hip_bfloat162 h[4]; ushort8v v; } pk;
            pk.h[0] = __float22bfloat162_rn(make_float2(o0, o1));
            pk.h[1] = __float22bfloat162_rn(make_float2(o2, o3));
            pk.h[2] = __float22bfloat162_rn(make_float2(o4, o5));
            pk.h[3] = __float22bfloat162_rn(make_float2(o6, o7));
            *(ushort8v*)(outrow + (size_t)jj * DMOD) = pk.v;
        }
    }
}

extern "C" void kernel_launch(void* const* d_in, const int* in_sizes, int n_in,
                              void* d_out, int out_size, void* d_ws, size_t ws_size,
                              hipStream_t stream) {
    const int* seq  = (const int*)d_in[0];
    const int* idx  = (const int*)d_in[1];
    const void* emb = d_in[2];   // fp32 or bf16 — probed on device
    const void* W   = d_in[3];
    const void* b   = d_in[4];
    float* tabs = (float*)d_ws;  // needs (2*2688+128+1)*4 = 22020 B

    precompute_tables<<<(NTAB + BDIM - 1) / BDIM, BDIM, 0, stream>>>(emb, W, b, tabs);
    pair_main<<<NROWS, BDIM, 0, stream>>>(seq, idx, tabs, d_out);
}